// Round 3
// baseline (520.967 us; speedup 1.0000x reference)
//
#include <hip/hip_runtime.h>
#include <math.h>

// Problem constants (fixed by the reference's setup_inputs)
constexpr int B = 2, G = 8, D = 16, H = 256, W = 320;
constexpr int HW = H * W;
constexpr float EPS = 1e-5f;

__device__ __forceinline__ float sigmoidf_(float x) {
    return 1.0f / (1.0f + __expf(-x));
}

__device__ __forceinline__ int reflect_(int i, int n) {
    // jnp.pad 'reflect' (edge not repeated): -1 -> 1, n -> n-2
    return i < 0 ? -i : (i >= n ? 2 * n - 2 - i : i);
}

// ---------------------------------------------------------------------------
// Fused kernel: PixelwiseNet + max-over-D + SimilarityNet, ONE read of x1.
// Block = 256 threads = 64 consecutive pixels x 4 depth-slots. Each thread
// handles 4 depths; every global load/store is 64-lane contiguous (256B).
// Max-over-D via per-thread partial + 4-slot LDS reduce.
// ---------------------------------------------------------------------------
__global__ __launch_bounds__(256) void k_fused(
    const float* __restrict__ x1,
    const float* __restrict__ depth_sample,
    const float* __restrict__ depth_min, const float* __restrict__ depth_max,
    const float* __restrict__ sw0, const float* __restrict__ sg0, const float* __restrict__ sb0,
    const float* __restrict__ sw1, const float* __restrict__ sg1, const float* __restrict__ sb1,
    const float* __restrict__ sw2, const float* __restrict__ sbias2,
    const float* __restrict__ pw0, const float* __restrict__ pg0, const float* __restrict__ pb0,
    const float* __restrict__ pw1, const float* __restrict__ pg1, const float* __restrict__ pb1,
    const float* __restrict__ pw2, const float* __restrict__ pbias2,
    float* __restrict__ s_out, float* __restrict__ xn_out)
{
    __shared__ float sPW0[128], sPB0[16], sPW1[128], sPB1[8], sPW2[8];
    __shared__ float sSW0[128], sSB0[16], sSW1[128], sSB1[8], sSW2[8];
    __shared__ float sPBias2, sSBias2;
    __shared__ float red[4][64];

    const int tid = threadIdx.x;
    const float rs = rsqrtf(1.0f + EPS);
    if (tid < 128) {
        sPW0[tid] = pw0[tid] * pg0[tid >> 3] * rs;
        sSW0[tid] = sw0[tid] * sg0[tid >> 3] * rs;
        sPW1[tid] = pw1[tid] * pg1[tid >> 4] * rs;
        sSW1[tid] = sw1[tid] * sg1[tid >> 4] * rs;
    } else if (tid < 144) {
        sPB0[tid - 128] = pb0[tid - 128];
    } else if (tid < 160) {
        sSB0[tid - 144] = sb0[tid - 144];
    } else if (tid < 168) {
        sPB1[tid - 160] = pb1[tid - 160];
    } else if (tid < 176) {
        sSB1[tid - 168] = sb1[tid - 168];
    } else if (tid < 184) {
        sPW2[tid - 176] = pw2[tid - 176];
    } else if (tid < 192) {
        sSW2[tid - 184] = sw2[tid - 184];
    } else if (tid == 192) {
        sPBias2 = pbias2[0];
    } else if (tid == 193) {
        sSBias2 = sbias2[0];
    }
    __syncthreads();

    const int pi = tid & 63;          // pixel lane (64 consecutive)
    const int slot = tid >> 6;        // depth slot (4 depths each)
    const int pid = blockIdx.x * 64 + pi;   // global pixel over B*HW
    const int b = pid / HW;
    const int p = pid - b * HW;

    const float* xbase = x1 + (size_t)b * G * D * HW + p;

    // ---- load 4 depth-slices of x (8 groups each) + pixelwise MLP head ----
    float x[4][8];
    float hpart = -3.4e38f;
    #pragma unroll
    for (int i = 0; i < 4; ++i) {
        const int dt = slot * 4 + i;
        #pragma unroll
        for (int g = 0; g < G; ++g)
            x[i][g] = xbase[(size_t)(g * D + dt) * HW];

        float l1[16];
        #pragma unroll
        for (int o = 0; o < 16; ++o) {
            float a = sPB0[o];
            #pragma unroll
            for (int c = 0; c < 8; ++c) a = fmaf(sPW0[o * 8 + c], x[i][c], a);
            l1[o] = fmaxf(a, 0.0f);
        }
        float l2[8];
        #pragma unroll
        for (int o = 0; o < 8; ++o) {
            float a = sPB1[o];
            #pragma unroll
            for (int c = 0; c < 16; ++c) a = fmaf(sPW1[o * 16 + c], l1[c], a);
            l2[o] = fmaxf(a, 0.0f);
        }
        float h3 = sPBias2;
        #pragma unroll
        for (int c = 0; c < 8; ++c) h3 = fmaf(sPW2[c], l2[c], h3);
        hpart = fmaxf(hpart, h3);
    }

    // ---- max over all 16 depths for this pixel ----
    red[slot][pi] = hpart;
    __syncthreads();
    const float hmax = fmaxf(fmaxf(red[0][pi], red[1][pi]),
                             fmaxf(red[2][pi], red[3][pi]));
    const float vw = sigmoidf_(hmax);

    const float inv_min = 1.0f / depth_min[b];
    const float inv_max = 1.0f / depth_max[b];
    const float rinv = 1.0f / (inv_min - inv_max);

    // ---- SimilarityNet on x*vw; write s, xn (all coalesced) ----
    #pragma unroll
    for (int i = 0; i < 4; ++i) {
        const int dt = slot * 4 + i;
        float xv[8];
        #pragma unroll
        for (int g = 0; g < G; ++g) xv[g] = x[i][g] * vw;

        float l1[16];
        #pragma unroll
        for (int o = 0; o < 16; ++o) {
            float a = sSB0[o];
            #pragma unroll
            for (int c = 0; c < 8; ++c) a = fmaf(sSW0[o * 8 + c], xv[c], a);
            l1[o] = fmaxf(a, 0.0f);
        }
        float l2[8];
        #pragma unroll
        for (int o = 0; o < 8; ++o) {
            float a = sSB1[o];
            #pragma unroll
            for (int c = 0; c < 16; ++c) a = fmaf(sSW1[o * 16 + c], l1[c], a);
            l2[o] = fmaxf(a, 0.0f);
        }
        float h3 = sSBias2;
        #pragma unroll
        for (int c = 0; c < 8; ++c) h3 = fmaf(sSW2[c], l2[c], h3);

        const size_t oidx = (size_t)(b * D + dt) * HW + p;
        s_out[oidx] = h3;
        const float ds = depth_sample[oidx];
        xn_out[oidx] = (1.0f / ds - inv_max) * rinv;
    }
}

// ---------------------------------------------------------------------------
// Kernel 2: neighbor gathers on s and xn, dw, score, softmax over D, depth.
// Block = 256 threads = 64 consecutive pixels x 4 depth-slots; offsets staged
// in LDS; tap indices hoisted out of the depth loop; softmax via LDS reduce.
// ---------------------------------------------------------------------------
__global__ __launch_bounds__(256) void k_score_depth(
    const float* __restrict__ s_arr, const float* __restrict__ xn,
    const float* __restrict__ offset, const float* __restrict__ depth_sample,
    float* __restrict__ out)
{
    __shared__ float off_lds[18][64];
    __shared__ float redA[4][64];
    __shared__ float redB[4][64];

    const int tid = threadIdx.x;
    const int pi = tid & 63;
    const int slot = tid >> 6;
    const int pg0_ = blockIdx.x * 64;      // first global pixel of block
    const int b = pg0_ / HW;
    const int pb0 = pg0_ - b * HW;         // first pixel-in-image (same row)
    const int p = pb0 + pi;
    const int h = p / W;
    const int w = p - h * W;

    // ---- stage per-pixel neighbor weights ----
    const float* ob = offset + (size_t)b * 18 * HW + pb0;
    for (int idx = tid; idx < 18 * 64; idx += 256) {
        const int s = idx >> 6, q = idx & 63;
        off_lds[s][q] = ob[(size_t)s * HW + q];
    }
    __syncthreads();

    // ---- reflected tap indices (depth-invariant) ----
    int a1s[9], a2s[9];
    {
        int ry1[3], ry2[3], cx1[3], cx2[3];
        #pragma unroll
        for (int i = 0; i < 3; ++i) {
            ry1[i] = reflect_(h + (i - 1) * 2, H) * W;
            ry2[i] = reflect_(h + (i - 1) * 4, H) * W;
            cx1[i] = reflect_(w + (i - 1) * 2, W);
            cx2[i] = reflect_(w + (i - 1) * 4, W);
        }
        #pragma unroll
        for (int s = 0; s < 9; ++s) {
            a1s[s] = ry1[s / 3] + cx1[s % 3];
            a2s[s] = ry2[s / 3] + cx2[s % 3];
        }
    }

    const size_t bbase = (size_t)b * D * HW;

    float score[4], dsv[4];
    #pragma unroll
    for (int i = 0; i < 4; ++i) {
        const int d = slot * 4 + i;
        const float* sd = s_arr + bbase + (size_t)d * HW;
        const float* xd = xn + bbase + (size_t)d * HW;
        float accs = 0.0f, accx = 0.0f;
        #pragma unroll
        for (int s = 0; s < 9; ++s) {
            const float w1 = off_lds[s + 9][pi];   // dilation-2 (X1) weight
            const float w2 = off_lds[s][pi];       // dilation-4 (X2) weight
            accs += 0.5f * (w1 * sd[a1s[s]] + w2 * sd[a2s[s]]);
            accx += 0.5f * (w1 * xd[a1s[s]] + w2 * xd[a2s[s]]);
        }
        const float xc = xd[p];
        const float diff = fminf(fabsf(accx - xc) * 40.0f, 4.0f);  // /0.025, clip 4
        const float dwv = sigmoidf_((2.0f - diff) * 2.0f);
        score[i] = accs * dwv;
        dsv[i] = depth_sample[bbase + (size_t)d * HW + p];
    }

    // ---- softmax over 16 depths (4 per thread x 4 slots) ----
    float mp = fmaxf(fmaxf(score[0], score[1]), fmaxf(score[2], score[3]));
    redA[slot][pi] = mp;
    __syncthreads();
    const float m = fmaxf(fmaxf(redA[0][pi], redA[1][pi]),
                          fmaxf(redA[2][pi], redA[3][pi]));
    float sp = 0.0f, ap = 0.0f;
    #pragma unroll
    for (int i = 0; i < 4; ++i) {
        const float e = __expf(score[i] - m);
        sp += e;
        ap = fmaf(dsv[i], e, ap);
    }
    __syncthreads();                  // redA read done before rewrite
    redA[slot][pi] = sp;
    redB[slot][pi] = ap;
    __syncthreads();
    if (slot == 0) {
        const float sum = redA[0][pi] + redA[1][pi] + redA[2][pi] + redA[3][pi];
        const float acc = redB[0][pi] + redB[1][pi] + redB[2][pi] + redB[3][pi];
        out[pg0_ + pi] = acc / sum;
    }
}

// ---------------------------------------------------------------------------
extern "C" void kernel_launch(void* const* d_in, const int* in_sizes, int n_in,
                              void* d_out, int out_size, void* d_ws, size_t ws_size,
                              hipStream_t stream)
{
    const float* x1           = (const float*)d_in[0];
    const float* offset       = (const float*)d_in[1];
    const float* depth_sample = (const float*)d_in[2];
    const float* depth_min    = (const float*)d_in[3];
    const float* depth_max    = (const float*)d_in[4];
    const float* s_w0 = (const float*)d_in[5];
    const float* s_g0 = (const float*)d_in[6];
    const float* s_b0 = (const float*)d_in[7];
    const float* s_w1 = (const float*)d_in[8];
    const float* s_g1 = (const float*)d_in[9];
    const float* s_b1 = (const float*)d_in[10];
    const float* s_w2 = (const float*)d_in[11];
    const float* s_bias2 = (const float*)d_in[12];
    const float* p_w0 = (const float*)d_in[13];
    const float* p_g0 = (const float*)d_in[14];
    const float* p_b0 = (const float*)d_in[15];
    const float* p_w1 = (const float*)d_in[16];
    const float* p_g1 = (const float*)d_in[17];
    const float* p_b1 = (const float*)d_in[18];
    const float* p_w2 = (const float*)d_in[19];
    const float* p_bias2 = (const float*)d_in[20];

    float* s_arr = (float*)d_ws;             // B*D*HW
    float* xn    = s_arr + (size_t)B * D * HW;

    k_fused<<<(B * HW) / 64, 256, 0, stream>>>(
        x1, depth_sample, depth_min, depth_max,
        s_w0, s_g0, s_b0, s_w1, s_g1, s_b1, s_w2, s_bias2,
        p_w0, p_g0, p_b0, p_w1, p_g1, p_b1, p_w2, p_bias2,
        s_arr, xn);

    k_score_depth<<<(B * HW) / 64, 256, 0, stream>>>(
        s_arr, xn, offset, depth_sample, (float*)d_out);
}

// Round 4
// 102.801 us; speedup vs baseline: 5.0677x; 5.0677x over previous
//
#include <hip/hip_runtime.h>
#include <math.h>

// Problem constants (fixed by the reference's setup_inputs)
constexpr int B = 2, G = 8, D = 16, H = 256, W = 320;
constexpr int HW = H * W;
constexpr float EPS = 1e-5f;

__device__ __forceinline__ float sigmoidf_(float x) {
    return 1.0f / (1.0f + __expf(-x));
}

__device__ __forceinline__ int reflect_(int i, int n) {
    // jnp.pad 'reflect' (edge not repeated): -1 -> 1, n -> n-2
    return i < 0 ? -i : (i >= n ? 2 * n - 2 - i : i);
}

// ---------------------------------------------------------------------------
// Fused kernel: PixelwiseNet + max-over-D + SimilarityNet, ONE read of x1.
// Block = 1024 threads = 64 consecutive pixels x 16 depths, ONE (pixel,depth)
// per thread -> only 8 x-values live across the reduce barrier (no spills;
// launch_bounds(1024) caps VGPR at 128). Every global access is a 256B
// wave-contiguous segment. Max-over-D via a [16][64] LDS tile.
// ---------------------------------------------------------------------------
__global__ __launch_bounds__(1024) void k_fused(
    const float* __restrict__ x1,
    const float* __restrict__ depth_sample,
    const float* __restrict__ depth_min, const float* __restrict__ depth_max,
    const float* __restrict__ sw0, const float* __restrict__ sg0, const float* __restrict__ sb0,
    const float* __restrict__ sw1, const float* __restrict__ sg1, const float* __restrict__ sb1,
    const float* __restrict__ sw2, const float* __restrict__ sbias2,
    const float* __restrict__ pw0, const float* __restrict__ pg0, const float* __restrict__ pb0,
    const float* __restrict__ pw1, const float* __restrict__ pg1, const float* __restrict__ pb1,
    const float* __restrict__ pw2, const float* __restrict__ pbias2,
    float* __restrict__ s_out, float* __restrict__ xn_out)
{
    __shared__ float sPW0[128], sPB0[16], sPW1[128], sPB1[8], sPW2[8];
    __shared__ float sSW0[128], sSB0[16], sSW1[128], sSB1[8], sSW2[8];
    __shared__ float sPBias2, sSBias2;
    __shared__ float red[16][64];

    const int tid = threadIdx.x;
    const float rs = rsqrtf(1.0f + EPS);
    if (tid < 128) {
        sPW0[tid] = pw0[tid] * pg0[tid >> 3] * rs;
        sSW0[tid] = sw0[tid] * sg0[tid >> 3] * rs;
        sPW1[tid] = pw1[tid] * pg1[tid >> 4] * rs;
        sSW1[tid] = sw1[tid] * sg1[tid >> 4] * rs;
    } else if (tid < 144) {
        sPB0[tid - 128] = pb0[tid - 128];
    } else if (tid < 160) {
        sSB0[tid - 144] = sb0[tid - 144];
    } else if (tid < 168) {
        sPB1[tid - 160] = pb1[tid - 160];
    } else if (tid < 176) {
        sSB1[tid - 168] = sb1[tid - 168];
    } else if (tid < 184) {
        sPW2[tid - 176] = pw2[tid - 176];
    } else if (tid < 192) {
        sSW2[tid - 184] = sw2[tid - 184];
    } else if (tid == 192) {
        sPBias2 = pbias2[0];
    } else if (tid == 193) {
        sSBias2 = sbias2[0];
    }
    __syncthreads();

    const int pi = tid & 63;          // pixel lane (64 consecutive)
    const int dt = tid >> 6;          // depth hypothesis (one per thread)
    const int pid = blockIdx.x * 64 + pi;   // global pixel over B*HW
    const int b = pid / HW;
    const int p = pid - b * HW;

    // ---- load this thread's 8 group values: x1[b, g, dt, p] (coalesced) ----
    const float* xb = x1 + ((size_t)(b * G * D) + dt) * HW + p;
    float x[G];
    #pragma unroll
    for (int g = 0; g < G; ++g) x[g] = xb[(size_t)g * D * HW];

    // ---- PixelwiseNet MLP head (sigmoid deferred; monotone) ----
    {
        float l1[16];
        #pragma unroll
        for (int o = 0; o < 16; ++o) {
            float a = sPB0[o];
            #pragma unroll
            for (int c = 0; c < 8; ++c) a = fmaf(sPW0[o * 8 + c], x[c], a);
            l1[o] = fmaxf(a, 0.0f);
        }
        float l2[8];
        #pragma unroll
        for (int o = 0; o < 8; ++o) {
            float a = sPB1[o];
            #pragma unroll
            for (int c = 0; c < 16; ++c) a = fmaf(sPW1[o * 16 + c], l1[c], a);
            l2[o] = fmaxf(a, 0.0f);
        }
        float h3 = sPBias2;
        #pragma unroll
        for (int c = 0; c < 8; ++c) h3 = fmaf(sPW2[c], l2[c], h3);
        red[dt][pi] = h3;
    }
    __syncthreads();

    // ---- max over the 16 depth hypotheses for this pixel ----
    float hmax = -3.4e38f;
    #pragma unroll
    for (int k = 0; k < 16; ++k) hmax = fmaxf(hmax, red[k][pi]);
    const float vw = sigmoidf_(hmax);

    // ---- SimilarityNet on x * vw (reuse registers) ----
    #pragma unroll
    for (int g = 0; g < G; ++g) x[g] *= vw;

    float l1[16];
    #pragma unroll
    for (int o = 0; o < 16; ++o) {
        float a = sSB0[o];
        #pragma unroll
        for (int c = 0; c < 8; ++c) a = fmaf(sSW0[o * 8 + c], x[c], a);
        l1[o] = fmaxf(a, 0.0f);
    }
    float l2[8];
    #pragma unroll
    for (int o = 0; o < 8; ++o) {
        float a = sSB1[o];
        #pragma unroll
        for (int c = 0; c < 16; ++c) a = fmaf(sSW1[o * 16 + c], l1[c], a);
        l2[o] = fmaxf(a, 0.0f);
    }
    float h3 = sSBias2;
    #pragma unroll
    for (int c = 0; c < 8; ++c) h3 = fmaf(sSW2[c], l2[c], h3);

    const size_t oidx = (size_t)(b * D + dt) * HW + p;
    s_out[oidx] = h3;

    // ---- normalized inverse depth ----
    const float inv_min = 1.0f / depth_min[b];
    const float inv_max = 1.0f / depth_max[b];
    const float ds = depth_sample[oidx];
    xn_out[oidx] = (1.0f / ds - inv_max) / (inv_min - inv_max);
}

// ---------------------------------------------------------------------------
// Kernel 2: neighbor gathers on s and xn, dw, score, softmax over D, depth.
// Block = 256 threads = 64 consecutive pixels x 4 depth-slots; offsets staged
// in LDS; tap indices hoisted out of the depth loop; softmax via LDS reduce.
// (measured ~10 us in round 2 -- unchanged)
// ---------------------------------------------------------------------------
__global__ __launch_bounds__(256) void k_score_depth(
    const float* __restrict__ s_arr, const float* __restrict__ xn,
    const float* __restrict__ offset, const float* __restrict__ depth_sample,
    float* __restrict__ out)
{
    __shared__ float off_lds[18][64];
    __shared__ float redA[4][64];
    __shared__ float redB[4][64];

    const int tid = threadIdx.x;
    const int pi = tid & 63;
    const int slot = tid >> 6;
    const int pg0_ = blockIdx.x * 64;      // first global pixel of block
    const int b = pg0_ / HW;
    const int pb0 = pg0_ - b * HW;         // first pixel-in-image (same row)
    const int p = pb0 + pi;
    const int h = p / W;
    const int w = p - h * W;

    // ---- stage per-pixel neighbor weights ----
    const float* ob = offset + (size_t)b * 18 * HW + pb0;
    for (int idx = tid; idx < 18 * 64; idx += 256) {
        const int s = idx >> 6, q = idx & 63;
        off_lds[s][q] = ob[(size_t)s * HW + q];
    }
    __syncthreads();

    // ---- reflected tap indices (depth-invariant) ----
    int a1s[9], a2s[9];
    {
        int ry1[3], ry2[3], cx1[3], cx2[3];
        #pragma unroll
        for (int i = 0; i < 3; ++i) {
            ry1[i] = reflect_(h + (i - 1) * 2, H) * W;
            ry2[i] = reflect_(h + (i - 1) * 4, H) * W;
            cx1[i] = reflect_(w + (i - 1) * 2, W);
            cx2[i] = reflect_(w + (i - 1) * 4, W);
        }
        #pragma unroll
        for (int s = 0; s < 9; ++s) {
            a1s[s] = ry1[s / 3] + cx1[s % 3];
            a2s[s] = ry2[s / 3] + cx2[s % 3];
        }
    }

    const size_t bbase = (size_t)b * D * HW;

    float score[4], dsv[4];
    #pragma unroll
    for (int i = 0; i < 4; ++i) {
        const int d = slot * 4 + i;
        const float* sd = s_arr + bbase + (size_t)d * HW;
        const float* xd = xn + bbase + (size_t)d * HW;
        float accs = 0.0f, accx = 0.0f;
        #pragma unroll
        for (int s = 0; s < 9; ++s) {
            const float w1 = off_lds[s + 9][pi];   // dilation-2 (X1) weight
            const float w2 = off_lds[s][pi];       // dilation-4 (X2) weight
            accs += 0.5f * (w1 * sd[a1s[s]] + w2 * sd[a2s[s]]);
            accx += 0.5f * (w1 * xd[a1s[s]] + w2 * xd[a2s[s]]);
        }
        const float xc = xd[p];
        const float diff = fminf(fabsf(accx - xc) * 40.0f, 4.0f);  // /0.025, clip 4
        const float dwv = sigmoidf_((2.0f - diff) * 2.0f);
        score[i] = accs * dwv;
        dsv[i] = depth_sample[bbase + (size_t)d * HW + p];
    }

    // ---- softmax over 16 depths (4 per thread x 4 slots) ----
    float mp = fmaxf(fmaxf(score[0], score[1]), fmaxf(score[2], score[3]));
    redA[slot][pi] = mp;
    __syncthreads();
    const float m = fmaxf(fmaxf(redA[0][pi], redA[1][pi]),
                          fmaxf(redA[2][pi], redA[3][pi]));
    float sp = 0.0f, ap = 0.0f;
    #pragma unroll
    for (int i = 0; i < 4; ++i) {
        const float e = __expf(score[i] - m);
        sp += e;
        ap = fmaf(dsv[i], e, ap);
    }
    __syncthreads();                  // redA read done before rewrite
    redA[slot][pi] = sp;
    redB[slot][pi] = ap;
    __syncthreads();
    if (slot == 0) {
        const float sum = redA[0][pi] + redA[1][pi] + redA[2][pi] + redA[3][pi];
        const float acc = redB[0][pi] + redB[1][pi] + redB[2][pi] + redB[3][pi];
        out[pg0_ + pi] = acc / sum;
    }
}

// ---------------------------------------------------------------------------
extern "C" void kernel_launch(void* const* d_in, const int* in_sizes, int n_in,
                              void* d_out, int out_size, void* d_ws, size_t ws_size,
                              hipStream_t stream)
{
    const float* x1           = (const float*)d_in[0];
    const float* offset       = (const float*)d_in[1];
    const float* depth_sample = (const float*)d_in[2];
    const float* depth_min    = (const float*)d_in[3];
    const float* depth_max    = (const float*)d_in[4];
    const float* s_w0 = (const float*)d_in[5];
    const float* s_g0 = (const float*)d_in[6];
    const float* s_b0 = (const float*)d_in[7];
    const float* s_w1 = (const float*)d_in[8];
    const float* s_g1 = (const float*)d_in[9];
    const float* s_b1 = (const float*)d_in[10];
    const float* s_w2 = (const float*)d_in[11];
    const float* s_bias2 = (const float*)d_in[12];
    const float* p_w0 = (const float*)d_in[13];
    const float* p_g0 = (const float*)d_in[14];
    const float* p_b0 = (const float*)d_in[15];
    const float* p_w1 = (const float*)d_in[16];
    const float* p_g1 = (const float*)d_in[17];
    const float* p_b1 = (const float*)d_in[18];
    const float* p_w2 = (const float*)d_in[19];
    const float* p_bias2 = (const float*)d_in[20];

    float* s_arr = (float*)d_ws;             // B*D*HW
    float* xn    = s_arr + (size_t)B * D * HW;

    k_fused<<<(B * HW) / 64, 1024, 0, stream>>>(
        x1, depth_sample, depth_min, depth_max,
        s_w0, s_g0, s_b0, s_w1, s_g1, s_b1, s_w2, s_bias2,
        p_w0, p_g0, p_b0, p_w1, p_g1, p_b1, p_w2, p_bias2,
        s_arr, xn);

    k_score_depth<<<(B * HW) / 64, 256, 0, stream>>>(
        s_arr, xn, offset, depth_sample, (float*)d_out);
}

// Round 5
// 95.107 us; speedup vs baseline: 5.4777x; 1.0809x over previous
//
#include <hip/hip_runtime.h>
#include <math.h>

// Problem constants (fixed by the reference's setup_inputs)
constexpr int B = 2, G = 8, D = 16, H = 256, W = 320;
constexpr int HW = H * W;
constexpr float EPS = 1e-5f;

__device__ __forceinline__ float sigmoidf_(float x) {
    return 1.0f / (1.0f + __expf(-x));
}

__device__ __forceinline__ int reflect_(int i, int n) {
    // jnp.pad 'reflect' (edge not repeated): -1 -> 1, n -> n-2
    return i < 0 ? -i : (i >= n ? 2 * n - 2 - i : i);
}

// ---------------------------------------------------------------------------
// Two-pixel MLP 8->16(ReLU)->8(ReLU)->1. Weights fetched as float4 from LDS
// (ds_read_b128, broadcast); each weight feeds BOTH pixels' FMA chains.
// ---------------------------------------------------------------------------
__device__ __forceinline__ void mlp2_(
    const float4* __restrict__ W0, const float* __restrict__ B0,
    const float4* __restrict__ W1, const float* __restrict__ B1,
    const float4* __restrict__ W2, const float bias2,
    const float xa[8], const float xb[8], float& ha, float& hb)
{
    float l1a[16], l1b[16];
    #pragma unroll
    for (int o = 0; o < 16; ++o) {
        const float4 w0 = W0[o * 2 + 0];
        const float4 w1 = W0[o * 2 + 1];
        float aa = B0[o], ab = B0[o];
        aa = fmaf(w0.x, xa[0], aa); ab = fmaf(w0.x, xb[0], ab);
        aa = fmaf(w0.y, xa[1], aa); ab = fmaf(w0.y, xb[1], ab);
        aa = fmaf(w0.z, xa[2], aa); ab = fmaf(w0.z, xb[2], ab);
        aa = fmaf(w0.w, xa[3], aa); ab = fmaf(w0.w, xb[3], ab);
        aa = fmaf(w1.x, xa[4], aa); ab = fmaf(w1.x, xb[4], ab);
        aa = fmaf(w1.y, xa[5], aa); ab = fmaf(w1.y, xb[5], ab);
        aa = fmaf(w1.z, xa[6], aa); ab = fmaf(w1.z, xb[6], ab);
        aa = fmaf(w1.w, xa[7], aa); ab = fmaf(w1.w, xb[7], ab);
        l1a[o] = fmaxf(aa, 0.0f); l1b[o] = fmaxf(ab, 0.0f);
    }
    float l2a[8], l2b[8];
    #pragma unroll
    for (int o = 0; o < 8; ++o) {
        float aa = B1[o], ab = B1[o];
        #pragma unroll
        for (int c4 = 0; c4 < 4; ++c4) {
            const float4 w = W1[o * 4 + c4];
            aa = fmaf(w.x, l1a[c4 * 4 + 0], aa); ab = fmaf(w.x, l1b[c4 * 4 + 0], ab);
            aa = fmaf(w.y, l1a[c4 * 4 + 1], aa); ab = fmaf(w.y, l1b[c4 * 4 + 1], ab);
            aa = fmaf(w.z, l1a[c4 * 4 + 2], aa); ab = fmaf(w.z, l1b[c4 * 4 + 2], ab);
            aa = fmaf(w.w, l1a[c4 * 4 + 3], aa); ab = fmaf(w.w, l1b[c4 * 4 + 3], ab);
        }
        l2a[o] = fmaxf(aa, 0.0f); l2b[o] = fmaxf(ab, 0.0f);
    }
    float h3a = bias2, h3b = bias2;
    #pragma unroll
    for (int c4 = 0; c4 < 2; ++c4) {
        const float4 w = W2[c4];
        h3a = fmaf(w.x, l2a[c4 * 4 + 0], h3a); h3b = fmaf(w.x, l2b[c4 * 4 + 0], h3b);
        h3a = fmaf(w.y, l2a[c4 * 4 + 1], h3a); h3b = fmaf(w.y, l2b[c4 * 4 + 1], h3b);
        h3a = fmaf(w.z, l2a[c4 * 4 + 2], h3a); h3b = fmaf(w.z, l2b[c4 * 4 + 2], h3b);
        h3a = fmaf(w.w, l2a[c4 * 4 + 3], h3a); h3b = fmaf(w.w, l2b[c4 * 4 + 3], h3b);
    }
    ha = h3a; hb = h3b;
}

// ---------------------------------------------------------------------------
// Fused: PixelwiseNet + max-over-D + SimilarityNet, ONE read of x1.
// Block = 512 threads = 16 depths x 32 pixel-pairs (64 consecutive pixels).
// Each thread: 2 pixels at 1 depth -> weight reads amortized 2x, two
// independent FMA chains for ILP, float2 global traffic. Max-over-D via a
// [16][64] LDS tile (float2, broadcast/2-way reads).
// ---------------------------------------------------------------------------
__global__ __launch_bounds__(512) void k_fused(
    const float* __restrict__ x1,
    const float* __restrict__ depth_sample,
    const float* __restrict__ depth_min, const float* __restrict__ depth_max,
    const float* __restrict__ sw0, const float* __restrict__ sg0, const float* __restrict__ sb0,
    const float* __restrict__ sw1, const float* __restrict__ sg1, const float* __restrict__ sb1,
    const float* __restrict__ sw2, const float* __restrict__ sbias2,
    const float* __restrict__ pw0, const float* __restrict__ pg0, const float* __restrict__ pb0,
    const float* __restrict__ pw1, const float* __restrict__ pg1, const float* __restrict__ pb1,
    const float* __restrict__ pw2, const float* __restrict__ pbias2,
    float* __restrict__ s_out, float* __restrict__ xn_out)
{
    __shared__ float4 sPW0[32], sPW1[32], sPW2[2];
    __shared__ float4 sSW0[32], sSW1[32], sSW2[2];
    __shared__ float sPB0[16], sPB1[8], sSB0[16], sSB1[8];
    __shared__ float sPBias2, sSBias2;
    __shared__ float red[16][64];

    const int tid = threadIdx.x;
    const float rs = rsqrtf(1.0f + EPS);
    if (tid < 128) {
        ((float*)sPW0)[tid] = pw0[tid] * pg0[tid >> 3] * rs;
        ((float*)sSW0)[tid] = sw0[tid] * sg0[tid >> 3] * rs;
        ((float*)sPW1)[tid] = pw1[tid] * pg1[tid >> 4] * rs;
        ((float*)sSW1)[tid] = sw1[tid] * sg1[tid >> 4] * rs;
    } else if (tid < 144) {
        sPB0[tid - 128] = pb0[tid - 128];
    } else if (tid < 160) {
        sSB0[tid - 144] = sb0[tid - 144];
    } else if (tid < 168) {
        sPB1[tid - 160] = pb1[tid - 160];
    } else if (tid < 176) {
        sSB1[tid - 168] = sb1[tid - 168];
    } else if (tid < 184) {
        ((float*)sPW2)[tid - 176] = pw2[tid - 176];
    } else if (tid < 192) {
        ((float*)sSW2)[tid - 184] = sw2[tid - 184];
    } else if (tid == 192) {
        sPBias2 = pbias2[0];
    } else if (tid == 193) {
        sSBias2 = sbias2[0];
    }
    __syncthreads();

    const int pl = tid & 31;          // pixel-pair lane (32 pairs = 64 px)
    const int dt = tid >> 5;          // depth hypothesis 0..15
    const int pid0 = blockIdx.x * 64 + 2 * pl;   // global pixel over B*HW
    const int b = pid0 / HW;
    const int p0 = pid0 - b * HW;

    // ---- load 2 pixels x 8 groups of x1 (float2, coalesced) ----
    const float* xp = x1 + ((size_t)(b * G * D) + dt) * HW + p0;
    float xa[8], xbv[8];
    #pragma unroll
    for (int g = 0; g < 8; ++g) {
        const float2 v = *reinterpret_cast<const float2*>(xp + (size_t)g * D * HW);
        xa[g] = v.x; xbv[g] = v.y;
    }

    // ---- PixelwiseNet head (sigmoid deferred; monotone) ----
    float ha, hb;
    mlp2_(sPW0, sPB0, sPW1, sPB1, sPW2, sPBias2, xa, xbv, ha, hb);
    *reinterpret_cast<float2*>(&red[dt][2 * pl]) = make_float2(ha, hb);
    __syncthreads();

    // ---- max over 16 depth hypotheses per pixel ----
    float ma = -3.4e38f, mb = -3.4e38f;
    #pragma unroll
    for (int k = 0; k < 16; ++k) {
        const float2 rv = *reinterpret_cast<const float2*>(&red[k][2 * pl]);
        ma = fmaxf(ma, rv.x); mb = fmaxf(mb, rv.y);
    }
    const float vwa = sigmoidf_(ma);
    const float vwb = sigmoidf_(mb);

    // ---- SimilarityNet on x * vw (reuse registers) ----
    #pragma unroll
    for (int g = 0; g < 8; ++g) { xa[g] *= vwa; xbv[g] *= vwb; }
    mlp2_(sSW0, sSB0, sSW1, sSB1, sSW2, sSBias2, xa, xbv, ha, hb);

    const size_t oidx = (size_t)(b * D + dt) * HW + p0;
    *reinterpret_cast<float2*>(s_out + oidx) = make_float2(ha, hb);

    // ---- normalized inverse depth ----
    const float inv_min = 1.0f / depth_min[b];
    const float inv_max = 1.0f / depth_max[b];
    const float rinv = 1.0f / (inv_min - inv_max);
    const float2 dsv = *reinterpret_cast<const float2*>(depth_sample + oidx);
    *reinterpret_cast<float2*>(xn_out + oidx) =
        make_float2((1.0f / dsv.x - inv_max) * rinv,
                    (1.0f / dsv.y - inv_max) * rinv);
}

// ---------------------------------------------------------------------------
// Kernel 2: neighbor gathers on s and xn, dw, score, softmax over D, depth.
// Block = 256 threads = 64 consecutive pixels x 4 depth-slots; offsets staged
// in LDS; tap indices hoisted out of the depth loop; softmax via LDS reduce.
// (measured ~10 us -- unchanged)
// ---------------------------------------------------------------------------
__global__ __launch_bounds__(256) void k_score_depth(
    const float* __restrict__ s_arr, const float* __restrict__ xn,
    const float* __restrict__ offset, const float* __restrict__ depth_sample,
    float* __restrict__ out)
{
    __shared__ float off_lds[18][64];
    __shared__ float redA[4][64];
    __shared__ float redB[4][64];

    const int tid = threadIdx.x;
    const int pi = tid & 63;
    const int slot = tid >> 6;
    const int pg0_ = blockIdx.x * 64;      // first global pixel of block
    const int b = pg0_ / HW;
    const int pb0 = pg0_ - b * HW;         // first pixel-in-image (same row)
    const int p = pb0 + pi;
    const int h = p / W;
    const int w = p - h * W;

    // ---- stage per-pixel neighbor weights ----
    const float* ob = offset + (size_t)b * 18 * HW + pb0;
    for (int idx = tid; idx < 18 * 64; idx += 256) {
        const int s = idx >> 6, q = idx & 63;
        off_lds[s][q] = ob[(size_t)s * HW + q];
    }
    __syncthreads();

    // ---- reflected tap indices (depth-invariant) ----
    int a1s[9], a2s[9];
    {
        int ry1[3], ry2[3], cx1[3], cx2[3];
        #pragma unroll
        for (int i = 0; i < 3; ++i) {
            ry1[i] = reflect_(h + (i - 1) * 2, H) * W;
            ry2[i] = reflect_(h + (i - 1) * 4, H) * W;
            cx1[i] = reflect_(w + (i - 1) * 2, W);
            cx2[i] = reflect_(w + (i - 1) * 4, W);
        }
        #pragma unroll
        for (int s = 0; s < 9; ++s) {
            a1s[s] = ry1[s / 3] + cx1[s % 3];
            a2s[s] = ry2[s / 3] + cx2[s % 3];
        }
    }

    const size_t bbase = (size_t)b * D * HW;

    float score[4], dsv[4];
    #pragma unroll
    for (int i = 0; i < 4; ++i) {
        const int d = slot * 4 + i;
        const float* sd = s_arr + bbase + (size_t)d * HW;
        const float* xd = xn + bbase + (size_t)d * HW;
        float accs = 0.0f, accx = 0.0f;
        #pragma unroll
        for (int s = 0; s < 9; ++s) {
            const float w1 = off_lds[s + 9][pi];   // dilation-2 (X1) weight
            const float w2 = off_lds[s][pi];       // dilation-4 (X2) weight
            accs += 0.5f * (w1 * sd[a1s[s]] + w2 * sd[a2s[s]]);
            accx += 0.5f * (w1 * xd[a1s[s]] + w2 * xd[a2s[s]]);
        }
        const float xc = xd[p];
        const float diff = fminf(fabsf(accx - xc) * 40.0f, 4.0f);  // /0.025, clip 4
        const float dwv = sigmoidf_((2.0f - diff) * 2.0f);
        score[i] = accs * dwv;
        dsv[i] = depth_sample[bbase + (size_t)d * HW + p];
    }

    // ---- softmax over 16 depths (4 per thread x 4 slots) ----
    float mp = fmaxf(fmaxf(score[0], score[1]), fmaxf(score[2], score[3]));
    redA[slot][pi] = mp;
    __syncthreads();
    const float m = fmaxf(fmaxf(redA[0][pi], redA[1][pi]),
                          fmaxf(redA[2][pi], redA[3][pi]));
    float sp = 0.0f, ap = 0.0f;
    #pragma unroll
    for (int i = 0; i < 4; ++i) {
        const float e = __expf(score[i] - m);
        sp += e;
        ap = fmaf(dsv[i], e, ap);
    }
    __syncthreads();                  // redA read done before rewrite
    redA[slot][pi] = sp;
    redB[slot][pi] = ap;
    __syncthreads();
    if (slot == 0) {
        const float sum = redA[0][pi] + redA[1][pi] + redA[2][pi] + redA[3][pi];
        const float acc = redB[0][pi] + redB[1][pi] + redB[2][pi] + redB[3][pi];
        out[pg0_ + pi] = acc / sum;
    }
}

// ---------------------------------------------------------------------------
extern "C" void kernel_launch(void* const* d_in, const int* in_sizes, int n_in,
                              void* d_out, int out_size, void* d_ws, size_t ws_size,
                              hipStream_t stream)
{
    const float* x1           = (const float*)d_in[0];
    const float* offset       = (const float*)d_in[1];
    const float* depth_sample = (const float*)d_in[2];
    const float* depth_min    = (const float*)d_in[3];
    const float* depth_max    = (const float*)d_in[4];
    const float* s_w0 = (const float*)d_in[5];
    const float* s_g0 = (const float*)d_in[6];
    const float* s_b0 = (const float*)d_in[7];
    const float* s_w1 = (const float*)d_in[8];
    const float* s_g1 = (const float*)d_in[9];
    const float* s_b1 = (const float*)d_in[10];
    const float* s_w2 = (const float*)d_in[11];
    const float* s_bias2 = (const float*)d_in[12];
    const float* p_w0 = (const float*)d_in[13];
    const float* p_g0 = (const float*)d_in[14];
    const float* p_b0 = (const float*)d_in[15];
    const float* p_w1 = (const float*)d_in[16];
    const float* p_g1 = (const float*)d_in[17];
    const float* p_b1 = (const float*)d_in[18];
    const float* p_w2 = (const float*)d_in[19];
    const float* p_bias2 = (const float*)d_in[20];

    float* s_arr = (float*)d_ws;             // B*D*HW
    float* xn    = s_arr + (size_t)B * D * HW;

    k_fused<<<(B * HW) / 64, 512, 0, stream>>>(
        x1, depth_sample, depth_min, depth_max,
        s_w0, s_g0, s_b0, s_w1, s_g1, s_b1, s_w2, s_bias2,
        p_w0, p_g0, p_b0, p_w1, p_g1, p_b1, p_w2, p_bias2,
        s_arr, xn);

    k_score_depth<<<(B * HW) / 64, 256, 0, stream>>>(
        s_arr, xn, offset, depth_sample, (float*)d_out);
}